// Round 8
// baseline (190.302 us; speedup 1.0000x reference)
//
#include <hip/hip_runtime.h>
#include <math.h>

#define B_  2
#define S_  2048
#define D_  1024
#define H_  16
#define DH_ 64
#define M_  (B_ * S_)   // 4096

typedef _Float16 half_t;
typedef __attribute__((ext_vector_type(8))) _Float16 h8;
typedef __attribute__((ext_vector_type(4))) _Float16 h4;
typedef __attribute__((ext_vector_type(4))) float   f32x4;

#define LOG2E 1.44269504088896f

// async global->LDS, 16 B per lane (lane-contiguous dest, m104/m108)
__device__ __forceinline__ void gll16(const half_t* g, half_t* l) {
    __builtin_amdgcn_global_load_lds(
        (__attribute__((address_space(1))) const void*)g,
        (__attribute__((address_space(3))) void*)l, 16, 0, 0);
}

// ---------------------------------------------------------------------------
// Prepass (fused): blocks 0..2047 convert x fp32->fp16; blocks 2048..3583
// transpose W [k][n] fp32 -> Wt [n][k] fp16 (3 matrices).
// ---------------------------------------------------------------------------
__global__ __launch_bounds__(256) void prep_k(
    const float* __restrict__ x, half_t* __restrict__ xh,
    const float* __restrict__ Wq, const float* __restrict__ Wk,
    const float* __restrict__ Wv, half_t* __restrict__ Wt)
{
    const int bx = blockIdx.x;
    if (bx < 2048) {
        const size_t i = ((size_t)bx * 256 + threadIdx.x) * 8;
        const float4 a = *(const float4*)(x + i);
        const float4 b = *(const float4*)(x + i + 4);
        h8 o;
        o[0] = (half_t)a.x; o[1] = (half_t)a.y; o[2] = (half_t)a.z; o[3] = (half_t)a.w;
        o[4] = (half_t)b.x; o[5] = (half_t)b.y; o[6] = (half_t)b.z; o[7] = (half_t)b.w;
        *(h8*)(xh + i) = o;
    } else {
        const int gb    = bx - 2048;                 // 0..1535
        const int which = gb >> 9;                   // 512 blocks per matrix
        const float* __restrict__ W = (which == 0) ? Wq : (which == 1) ? Wk : Wv;
        half_t* __restrict__ T = Wt + (size_t)which * D_ * D_;
        const int gw   = (gb & 511) * 4 + (threadIdx.x >> 6);   // 0..2047
        const int lane = threadIdx.x & 63;
        const int n    = (gw & 15) * 64 + lane;
        const int k0   = (gw >> 4) * 8;
        h8 o;
        #pragma unroll
        for (int t = 0; t < 8; ++t) o[t] = (half_t)W[(size_t)(k0 + t) * D_ + n];
        *(h8*)(T + (size_t)n * D_ + k0) = o;
    }
}

// ---------------------------------------------------------------------------
// Kernel 1: fused QKV projection — unchanged from r7 (8 waves, 32x64/wave,
// global_load_lds both operands, XCD swizzle, LDS-transpose epilogue).
// ---------------------------------------------------------------------------
__global__ __launch_bounds__(512) void qkv_gemm_f16(
    const half_t* __restrict__ xh, const half_t* __restrict__ Wt,
    const float* __restrict__ bq, const float* __restrict__ bk,
    const float* __restrict__ bv,
    half_t* __restrict__ Qo, half_t* __restrict__ Ko, half_t* __restrict__ Vt)
{
    const int lin = blockIdx.y * 24 + blockIdx.x;        // 0..767
    const int swz = (lin & 7) * 96 + (lin >> 3);
    const int n0g = (swz % 24) * 128;
    const int m0  = (swz / 24) * 128;
    const int which = n0g >> 10;
    const int n0    = n0g & 1023;
    const half_t* __restrict__ Wp  = Wt + (size_t)which * D_ * D_;
    const float* __restrict__ bias = (which == 0) ? bq : (which == 1) ? bk : bv;

    const int tid = threadIdx.x, lane = tid & 63, wave = tid >> 6;   // 0..7
    const int wm = (wave & 3) * 32, wn = (wave >> 2) * 64;
    const int ln = lane & 15, quad = lane >> 4;

    __shared__ __align__(16) half_t SMEM[128 * 136];
    half_t* const As = SMEM;              // 128*64 swizzled slots
    half_t* const Bs = SMEM + 128 * 64;   // 128*64 swizzled slots

    const int r0  = tid >> 3, c0 = tid & 7;
    const int cs  = c0 ^ (r0 & 7);
    const half_t* aS = xh + (size_t)(m0 + r0) * D_ + cs * 8;
    const half_t* bS = Wp + (size_t)(n0 + r0) * D_ + cs * 8;

    f32x4 acc[2][4];
    #pragma unroll
    for (int i = 0; i < 2; ++i)
        #pragma unroll
        for (int j = 0; j < 4; ++j) acc[i][j] = (f32x4){0.f, 0.f, 0.f, 0.f};

    for (int k0 = 0; k0 < D_; k0 += 64) {
        __syncthreads();
        gll16(aS,            &As[tid * 8]);
        gll16(aS + 64 * D_,  &As[(tid + 512) * 8]);
        gll16(bS,            &Bs[tid * 8]);
        gll16(bS + 64 * D_,  &Bs[(tid + 512) * 8]);
        aS += 64; bS += 64;
        __syncthreads();

        #pragma unroll
        for (int kc = 0; kc < 2; ++kc) {
            h8 af[2], bf[4];
            #pragma unroll
            for (int i = 0; i < 2; ++i) {
                const int r = wm + i * 16 + ln;
                af[i] = *(const h8*)&As[r * 64 + (((kc << 2) + quad) ^ (r & 7)) * 8];
            }
            #pragma unroll
            for (int j = 0; j < 4; ++j) {
                const int r = wn + j * 16 + ln;
                bf[j] = *(const h8*)&Bs[r * 64 + (((kc << 2) + quad) ^ (r & 7)) * 8];
            }
            #pragma unroll
            for (int i = 0; i < 2; ++i)
                #pragma unroll
                for (int j = 0; j < 4; ++j)
                    acc[i][j] = __builtin_amdgcn_mfma_f32_16x16x32_f16(
                        af[i], bf[j], acc[i][j], 0, 0, 0);
        }
    }

    if (which == 2) {
        #pragma unroll
        for (int j = 0; j < 4; ++j) {
            const int col = n0 + wn + j * 16 + ln;   // 0..1023
            const int h = col >> 6, d = col & 63;
            const float bb = bias[col];
            #pragma unroll
            for (int i = 0; i < 2; ++i) {
                const int sg = m0 + wm + i * 16 + quad * 4;   // global row
                const int b  = sg >> 11, srow = sg & 2047;
                h4 pv;
                #pragma unroll
                for (int r = 0; r < 4; ++r) pv[r] = (half_t)(acc[i][j][r] + bb);
                *(h4*)(Vt + (((size_t)(b * H_ + h) * DH_ + d) * S_ + srow)) = pv;
            }
        }
    } else {
        half_t* __restrict__ outp = (which == 0) ? Qo : Ko;
        __syncthreads();
        #pragma unroll
        for (int j = 0; j < 4; ++j) {
            const int col = wn + j * 16 + ln;
            const float bb = bias[n0 + col];
            #pragma unroll
            for (int i = 0; i < 2; ++i) {
                #pragma unroll
                for (int r = 0; r < 4; ++r) {
                    const int row = wm + i * 16 + quad * 4 + r;
                    float t = acc[i][j][r] + bb;
                    if (which == 0) {
                        const float u = t * fmaf(t * t, 0.0356774081f, 0.7978845608f);
                        const float e = __builtin_amdgcn_exp2f(u * -2.88539008178f);
                        t = t * __builtin_amdgcn_rcpf(1.0f + e) * LOG2E;
                    }
                    SMEM[row * 136 + col] = (half_t)t;
                }
            }
        }
        __syncthreads();
        const int cc = tid & 15;
        const int rr = tid >> 4;
        #pragma unroll
        for (int p = 0; p < 4; ++p) {
            const int row = p * 32 + rr;
            const h8 v = *(const h8*)&SMEM[row * 136 + cc * 8];
            *(h8*)(outp + (size_t)(m0 + row) * D_ + n0 + cc * 8) = v;
        }
    }
}

// ---------------------------------------------------------------------------
// Kernel 2: flash attention.  NEW this round: dual q-group waves — 4 waves
// x 32 q-rows (r0's decomposition) so every K/V fragment read feeds TWO
// MFMAs, halving LDS fragment traffic per MFMA.  r7 counters implied the
// LDS pipe was the busiest resource (~320 KB/CU/tile ≈ 60-75% of the LDS
// ceiling); this halves it (~176 KB).  All later levers retained: alias-
// free static double-buffer + 1 barrier/tile (r3), T13 defer-max (r6),
// setprio, XCD-bijective swizzle.  2 blocks/CU x 4 waves = 8 waves/CU —
// the occupancy cost is the bet; dbuf + 2-block decoupling must cover it.
// LDS = 4*8 + 18 = 50 KB.
// ---------------------------------------------------------------------------
#define DEFER_THR 10.0f
#define ATTN_TILE(KS, VS)                                                     \
    do {                                                                      \
        f32x4 sa[4], sb[4];                                                   \
        __builtin_amdgcn_s_setprio(1);                                        \
        _Pragma("unroll")                                                     \
        for (int j = 0; j < 4; ++j) {                                         \
            const int rK = j * 16 + ln;                                       \
            const h8 ka0 = *(const h8*)&KS[rK * 64 + ((quad)     ^ (rK & 7)) * 8]; \
            const h8 ka1 = *(const h8*)&KS[rK * 64 + ((quad + 4) ^ (rK & 7)) * 8]; \
            f32x4 t = (f32x4){0.f, 0.f, 0.f, 0.f};                            \
            t = __builtin_amdgcn_mfma_f32_16x16x32_f16(ka0, qa0, t, 0, 0, 0); \
            t = __builtin_amdgcn_mfma_f32_16x16x32_f16(ka1, qa1, t, 0, 0, 0); \
            sa[j] = t;                                                        \
            f32x4 u = (f32x4){0.f, 0.f, 0.f, 0.f};                            \
            u = __builtin_amdgcn_mfma_f32_16x16x32_f16(ka0, qc0, u, 0, 0, 0); \
            u = __builtin_amdgcn_mfma_f32_16x16x32_f16(ka1, qc1, u, 0, 0, 0); \
            sb[j] = u;                                                        \
        }                                                                     \
        __builtin_amdgcn_s_setprio(0);                                        \
        float mxa = sa[0][0], mxb = sb[0][0];                                 \
        _Pragma("unroll")                                                     \
        for (int j = 0; j < 4; ++j)                                           \
            _Pragma("unroll")                                                 \
            for (int r = 0; r < 4; ++r) {                                     \
                mxa = fmaxf(mxa, sa[j][r]);                                   \
                mxb = fmaxf(mxb, sb[j][r]);                                   \
            }                                                                 \
        mxa = fmaxf(mxa, __shfl_xor(mxa, 16, 64));                            \
        mxa = fmaxf(mxa, __shfl_xor(mxa, 32, 64));                            \
        mxb = fmaxf(mxb, __shfl_xor(mxb, 16, 64));                            \
        mxb = fmaxf(mxb, __shfl_xor(mxb, 32, 64));                            \
        if (__ballot(mxa > m_a + DEFER_THR || mxb > m_b + DEFER_THR)) {       \
            const float mna = fmaxf(m_a, mxa);                                \
            const float mnb = fmaxf(m_b, mxb);                                \
            const float ala = __builtin_amdgcn_exp2f(m_a - mna);              \
            const float alb = __builtin_amdgcn_exp2f(m_b - mnb);              \
            m_a = mna; m_b = mnb;                                             \
            float ra[4], rb[4];                                               \
            _Pragma("unroll")                                                 \
            for (int r = 0; r < 4; ++r) {                                     \
                ra[r] = __shfl(ala, quad * 4 + r, 64);                        \
                rb[r] = __shfl(alb, quad * 4 + r, 64);                        \
            }                                                                 \
            _Pragma("unroll")                                                 \
            for (int r = 0; r < 4; ++r) {                                     \
                la[r] *= ra[r]; lb[r] *= rb[r];                               \
                _Pragma("unroll")                                             \
                for (int j = 0; j < 4; ++j) {                                 \
                    Oa[j][r] *= ra[r]; Ob[j][r] *= rb[r];                     \
                }                                                             \
            }                                                                 \
        }                                                                     \
        _Pragma("unroll")                                                     \
        for (int j = 0; j < 4; ++j) {                                         \
            h4 pva, pvb;                                                      \
            _Pragma("unroll")                                                 \
            for (int r = 0; r < 4; ++r) {                                     \
                pva[r] = (half_t)__builtin_amdgcn_exp2f(sa[j][r] - m_a);      \
                pvb[r] = (half_t)__builtin_amdgcn_exp2f(sb[j][r] - m_b);      \
            }                                                                 \
            *(h4*)&QPs[wave * 32 + ln][j * 16 + quad * 4]      = pva;         \
            *(h4*)&QPs[wave * 32 + 16 + ln][j * 16 + quad * 4] = pvb;         \
        }                                                                     \
        const h8 pa0 = *(const h8*)&QPs[wave * 32 + ln][quad * 8];            \
        const h8 pa1 = *(const h8*)&QPs[wave * 32 + ln][32 + quad * 8];       \
        const h8 pb0 = *(const h8*)&QPs[wave * 32 + 16 + ln][quad * 8];       \
        const h8 pb1 = *(const h8*)&QPs[wave * 32 + 16 + ln][32 + quad * 8];  \
        __builtin_amdgcn_s_setprio(1);                                        \
        _Pragma("unroll")                                                     \
        for (int j = 0; j < 4; ++j) {                                         \
            const int rV = j * 16 + ln;                                       \
            const h8 vb0 = *(const h8*)&VS[rV * 64 + ((quad)     ^ (rV & 7)) * 8]; \
            const h8 vb1 = *(const h8*)&VS[rV * 64 + ((quad + 4) ^ (rV & 7)) * 8]; \
            Oa[j] = __builtin_amdgcn_mfma_f32_16x16x32_f16(pa0, vb0, Oa[j], 0, 0, 0); \
            Oa[j] = __builtin_amdgcn_mfma_f32_16x16x32_f16(pa1, vb1, Oa[j], 0, 0, 0); \
            Ob[j] = __builtin_amdgcn_mfma_f32_16x16x32_f16(pb0, vb0, Ob[j], 0, 0, 0); \
            Ob[j] = __builtin_amdgcn_mfma_f32_16x16x32_f16(pb1, vb1, Ob[j], 0, 0, 0); \
        }                                                                     \
        la = __builtin_amdgcn_mfma_f32_16x16x32_f16(pa0, ones8, la, 0, 0, 0); \
        la = __builtin_amdgcn_mfma_f32_16x16x32_f16(pa1, ones8, la, 0, 0, 0); \
        lb = __builtin_amdgcn_mfma_f32_16x16x32_f16(pb0, ones8, lb, 0, 0, 0); \
        lb = __builtin_amdgcn_mfma_f32_16x16x32_f16(pb1, ones8, lb, 0, 0, 0); \
        __builtin_amdgcn_s_setprio(0);                                        \
    } while (0)

__global__ __launch_bounds__(256) void attn_f16(
    const half_t* __restrict__ Q, const half_t* __restrict__ K,
    const half_t* __restrict__ Vt, float* __restrict__ out)
{
    const int tid  = threadIdx.x;
    const int lane = tid & 63;
    const int wave = tid >> 6;           // 0..3
    const int ln   = lane & 15;
    const int quad = lane >> 4;

    // XCD-bijective swizzle: 512 blocks = 8 x 64
    const int lin = blockIdx.y * 16 + blockIdx.x;        // 0..511
    const int swz = (lin & 7) * 64 + (lin >> 3);
    const int bh  = swz >> 4;            // 0..31
    const int b   = bh >> 4;
    const int h   = bh & 15;
    const int q0  = (swz & 15) * 128;

    const half_t* __restrict__ Qb  = Q  + (size_t)b * S_ * D_ + h * DH_;
    const half_t* __restrict__ Kb  = K  + (size_t)b * S_ * D_ + h * DH_;
    const half_t* __restrict__ Vtb = Vt + (size_t)bh * DH_ * S_;

    // four DISTINCT static buffers -> alias-free prefetch (r3)
    __shared__ __align__(16) half_t Ks0[64 * 64];
    __shared__ __align__(16) half_t Vs0[64 * 64];
    __shared__ __align__(16) half_t Ks1[64 * 64];
    __shared__ __align__(16) half_t Vs1[64 * 64];
    __shared__ __align__(16) half_t QPs[128][72];   // Q tile, then P bands

    // staging: 512 chunks over 256 threads (2 each; +32 rows, same XOR)
    const int sr  = tid >> 3, sc0 = tid & 7;
    const int scs = sc0 ^ (sr & 7);
    const half_t* kS = Kb  + (size_t)sr * D_ + scs * 8;   // += 64*D_ per tile
    const half_t* vS = Vtb + (size_t)sr * S_ + scs * 8;   // += 64   per tile

    // ---- prologue: stage tile 0 into buffer 0 (overlaps the Q load) ----
    gll16(kS,           &Ks0[tid * 8]);
    gll16(kS + 32 * D_, &Ks0[(tid + 256) * 8]);
    gll16(vS,           &Vs0[tid * 8]);
    gll16(vS + 32 * S_, &Vs0[(tid + 256) * 8]);
    kS += 64 * D_; vS += 64;

    // ---- load Q tile (128x64), hoist both q-group fragment pairs ----
    #pragma unroll
    for (int l = 0; l < 4; ++l) {
        const int c = tid + l * 256;                 // 0..1023
        const int r = c >> 3, k8 = c & 7;
        *(h8*)&QPs[r][k8 * 8] = *(const h8*)(Qb + (size_t)(q0 + r) * D_ + k8 * 8);
    }
    __syncthreads();    // implicit vmcnt(0)+lgkmcnt(0): Q AND tile-0 ready
    const h8 qa0 = *(const h8*)&QPs[wave * 32 + ln][quad * 8];
    const h8 qa1 = *(const h8*)&QPs[wave * 32 + ln][32 + quad * 8];
    const h8 qc0 = *(const h8*)&QPs[wave * 32 + 16 + ln][quad * 8];
    const h8 qc1 = *(const h8*)&QPs[wave * 32 + 16 + ln][32 + quad * 8];

    h8 ones8;
    #pragma unroll
    for (int t = 0; t < 8; ++t) ones8[t] = (half_t)1.0f;

    f32x4 Oa[4], Ob[4];
    #pragma unroll
    for (int j = 0; j < 4; ++j) {
        Oa[j] = (f32x4){0.f, 0.f, 0.f, 0.f};
        Ob[j] = (f32x4){0.f, 0.f, 0.f, 0.f};
    }
    f32x4 la = (f32x4){0.f, 0.f, 0.f, 0.f};
    f32x4 lb = (f32x4){0.f, 0.f, 0.f, 0.f};
    float m_a = -INFINITY, m_b = -INFINITY;   // rows wave*32+ln, +16+ln

    // 32 k-tiles, unrolled x2: buffer identity is compile-time constant.
    for (int it = 0; it < 16; ++it) {
        // phase A: prefetch tile (2it+1) into buf1, compute buf0
        gll16(kS,           &Ks1[tid * 8]);
        gll16(kS + 32 * D_, &Ks1[(tid + 256) * 8]);
        gll16(vS,           &Vs1[tid * 8]);
        gll16(vS + 32 * S_, &Vs1[(tid + 256) * 8]);
        kS += 64 * D_; vS += 64;
        ATTN_TILE(Ks0, Vs0);
        __syncthreads();          // drains buf1 DMA; all done reading buf0

        // phase B: prefetch tile (2it+2) into buf0, compute buf1
        if (it < 15) {
            gll16(kS,           &Ks0[tid * 8]);
            gll16(kS + 32 * D_, &Ks0[(tid + 256) * 8]);
            gll16(vS,           &Vs0[tid * 8]);
            gll16(vS + 32 * S_, &Vs0[(tid + 256) * 8]);
            kS += 64 * D_; vS += 64;
        }
        ATTN_TILE(Ks1, Vs1);
        __syncthreads();          // drains buf0 DMA; all done reading buf1
    }

    // ---- epilogue: normalize, store fp32 ----
    #pragma unroll
    for (int r = 0; r < 4; ++r) {
        const float iva = 1.0f / la[r];
        const float ivb = 1.0f / lb[r];
        const int rowa = q0 + wave * 32 + quad * 4 + r;
        const int rowb = rowa + 16;
        #pragma unroll
        for (int j = 0; j < 4; ++j) {
            out[((size_t)b * S_ + rowa) * D_ + h * DH_ + j * 16 + ln] = Oa[j][r] * iva;
            out[((size_t)b * S_ + rowb) * D_ + h * DH_ + j * 16 + ln] = Ob[j][r] * ivb;
        }
    }
}

// ---------------------------------------------------------------------------
extern "C" void kernel_launch(void* const* d_in, const int* in_sizes, int n_in,
                              void* d_out, int out_size, void* d_ws, size_t ws_size,
                              hipStream_t stream) {
    const float* x  = (const float*)d_in[0];
    const float* Wq = (const float*)d_in[1];
    const float* bq = (const float*)d_in[2];
    const float* Wk = (const float*)d_in[3];
    const float* bk = (const float*)d_in[4];
    const float* Wv = (const float*)d_in[5];
    const float* bv = (const float*)d_in[6];
    float* out = (float*)d_out;

    const size_t nmd = (size_t)M_ * D_;   // 4M
    const size_t ndd = (size_t)D_ * D_;   // 1M
    half_t* xh  = (half_t*)d_ws;          // 4M halves
    half_t* Wt  = xh + nmd;               // 3M
    half_t* Qh  = Wt + 3 * ndd;           // 4M
    half_t* Kh  = Qh + nmd;               // 4M
    half_t* Vtw = Kh + nmd;               // 4M  (38 MB total)

    prep_k<<<2048 + 1536, 256, 0, stream>>>(x, xh, Wq, Wk, Wv, Wt);
    qkv_gemm_f16<<<dim3(3 * D_ / 128, M_ / 128), 512, 0, stream>>>(
        xh, Wt, bq, bk, bv, Qh, Kh, Vtw);
    attn_f16<<<dim3(S_ / 128, B_ * H_), 256, 0, stream>>>(Qh, Kh, Vtw, out);
}

// Round 9
// 168.258 us; speedup vs baseline: 1.1310x; 1.1310x over previous
//
#include <hip/hip_runtime.h>
#include <math.h>

#define B_  2
#define S_  2048
#define D_  1024
#define H_  16
#define DH_ 64
#define M_  (B_ * S_)   // 4096

typedef _Float16 half_t;
typedef __attribute__((ext_vector_type(8))) _Float16 h8;
typedef __attribute__((ext_vector_type(4))) _Float16 h4;
typedef __attribute__((ext_vector_type(4))) float   f32x4;

#define LOG2E 1.44269504088896f

// async global->LDS, 16 B per lane (lane-contiguous dest, m104/m108)
__device__ __forceinline__ void gll16(const half_t* g, half_t* l) {
    __builtin_amdgcn_global_load_lds(
        (__attribute__((address_space(1))) const void*)g,
        (__attribute__((address_space(3))) void*)l, 16, 0, 0);
}

// ---------------------------------------------------------------------------
// Prepass (fused): blocks 0..2047 convert x fp32->fp16; blocks 2048..3583
// transpose W [k][n] fp32 -> Wt [n][k] fp16 (3 matrices).
// ---------------------------------------------------------------------------
__global__ __launch_bounds__(256) void prep_k(
    const float* __restrict__ x, half_t* __restrict__ xh,
    const float* __restrict__ Wq, const float* __restrict__ Wk,
    const float* __restrict__ Wv, half_t* __restrict__ Wt)
{
    const int bx = blockIdx.x;
    if (bx < 2048) {
        const size_t i = ((size_t)bx * 256 + threadIdx.x) * 8;
        const float4 a = *(const float4*)(x + i);
        const float4 b = *(const float4*)(x + i + 4);
        h8 o;
        o[0] = (half_t)a.x; o[1] = (half_t)a.y; o[2] = (half_t)a.z; o[3] = (half_t)a.w;
        o[4] = (half_t)b.x; o[5] = (half_t)b.y; o[6] = (half_t)b.z; o[7] = (half_t)b.w;
        *(h8*)(xh + i) = o;
    } else {
        const int gb    = bx - 2048;                 // 0..1535
        const int which = gb >> 9;                   // 512 blocks per matrix
        const float* __restrict__ W = (which == 0) ? Wq : (which == 1) ? Wk : Wv;
        half_t* __restrict__ T = Wt + (size_t)which * D_ * D_;
        const int gw   = (gb & 511) * 4 + (threadIdx.x >> 6);   // 0..2047
        const int lane = threadIdx.x & 63;
        const int n    = (gw & 15) * 64 + lane;
        const int k0   = (gw >> 4) * 8;
        h8 o;
        #pragma unroll
        for (int t = 0; t < 8; ++t) o[t] = (half_t)W[(size_t)(k0 + t) * D_ + n];
        *(h8*)(T + (size_t)n * D_ + k0) = o;
    }
}

// ---------------------------------------------------------------------------
// Kernel 1: fused QKV projection — r7 structure (8 waves, 32x64/wave,
// global_load_lds both operands, LDS-transpose epilogue).  NEW this round:
// column-strip XCD swizzle.  r6's counters showed FETCH_SIZE 59.6 MB vs
// ~22 MB of input — the old 4m x 24n per-XCD chunk made every XCD touch all
// 24 B-panels (6 MB Wt > 4 MB L2/XCD -> thrash).  Now each XCD owns 3
// n-tiles x 32 m-tiles: B working set 0.75 MB (L2-resident all kernel),
// A-panels reused by 3 consecutive blocks.
// ---------------------------------------------------------------------------
__global__ __launch_bounds__(512) void qkv_gemm_f16(
    const half_t* __restrict__ xh, const half_t* __restrict__ Wt,
    const float* __restrict__ bq, const float* __restrict__ bk,
    const float* __restrict__ bv,
    half_t* __restrict__ Qo, half_t* __restrict__ Ko, half_t* __restrict__ Vt)
{
    // column-strip XCD swizzle: xcd = lin&7 owns n-tiles {3*xcd..3*xcd+2}
    const int lin = blockIdx.y * 24 + blockIdx.x;        // 0..767
    const int xcd = lin & 7;
    const int idx = lin >> 3;                            // 0..95
    const int n0g = (xcd * 3 + idx % 3) * 128;
    const int m0  = (idx / 3) * 128;
    const int which = n0g >> 10;
    const int n0    = n0g & 1023;
    const half_t* __restrict__ Wp  = Wt + (size_t)which * D_ * D_;
    const float* __restrict__ bias = (which == 0) ? bq : (which == 1) ? bk : bv;

    const int tid = threadIdx.x, lane = tid & 63, wave = tid >> 6;   // 0..7
    const int wm = (wave & 3) * 32, wn = (wave >> 2) * 64;
    const int ln = lane & 15, quad = lane >> 4;

    __shared__ __align__(16) half_t SMEM[128 * 136];
    half_t* const As = SMEM;              // 128*64 swizzled slots
    half_t* const Bs = SMEM + 128 * 64;   // 128*64 swizzled slots

    const int r0  = tid >> 3, c0 = tid & 7;
    const int cs  = c0 ^ (r0 & 7);
    const half_t* aS = xh + (size_t)(m0 + r0) * D_ + cs * 8;
    const half_t* bS = Wp + (size_t)(n0 + r0) * D_ + cs * 8;

    f32x4 acc[2][4];
    #pragma unroll
    for (int i = 0; i < 2; ++i)
        #pragma unroll
        for (int j = 0; j < 4; ++j) acc[i][j] = (f32x4){0.f, 0.f, 0.f, 0.f};

    for (int k0 = 0; k0 < D_; k0 += 64) {
        __syncthreads();
        gll16(aS,            &As[tid * 8]);
        gll16(aS + 64 * D_,  &As[(tid + 512) * 8]);
        gll16(bS,            &Bs[tid * 8]);
        gll16(bS + 64 * D_,  &Bs[(tid + 512) * 8]);
        aS += 64; bS += 64;
        __syncthreads();

        #pragma unroll
        for (int kc = 0; kc < 2; ++kc) {
            h8 af[2], bf[4];
            #pragma unroll
            for (int i = 0; i < 2; ++i) {
                const int r = wm + i * 16 + ln;
                af[i] = *(const h8*)&As[r * 64 + (((kc << 2) + quad) ^ (r & 7)) * 8];
            }
            #pragma unroll
            for (int j = 0; j < 4; ++j) {
                const int r = wn + j * 16 + ln;
                bf[j] = *(const h8*)&Bs[r * 64 + (((kc << 2) + quad) ^ (r & 7)) * 8];
            }
            #pragma unroll
            for (int i = 0; i < 2; ++i)
                #pragma unroll
                for (int j = 0; j < 4; ++j)
                    acc[i][j] = __builtin_amdgcn_mfma_f32_16x16x32_f16(
                        af[i], bf[j], acc[i][j], 0, 0, 0);
        }
    }

    if (which == 2) {
        #pragma unroll
        for (int j = 0; j < 4; ++j) {
            const int col = n0 + wn + j * 16 + ln;   // 0..1023
            const int h = col >> 6, d = col & 63;
            const float bb = bias[col];
            #pragma unroll
            for (int i = 0; i < 2; ++i) {
                const int sg = m0 + wm + i * 16 + quad * 4;   // global row
                const int b  = sg >> 11, srow = sg & 2047;
                h4 pv;
                #pragma unroll
                for (int r = 0; r < 4; ++r) pv[r] = (half_t)(acc[i][j][r] + bb);
                *(h4*)(Vt + (((size_t)(b * H_ + h) * DH_ + d) * S_ + srow)) = pv;
            }
        }
    } else {
        half_t* __restrict__ outp = (which == 0) ? Qo : Ko;
        __syncthreads();
        #pragma unroll
        for (int j = 0; j < 4; ++j) {
            const int col = wn + j * 16 + ln;
            const float bb = bias[n0 + col];
            #pragma unroll
            for (int i = 0; i < 2; ++i) {
                #pragma unroll
                for (int r = 0; r < 4; ++r) {
                    const int row = wm + i * 16 + quad * 4 + r;
                    float t = acc[i][j][r] + bb;
                    if (which == 0) {
                        const float u = t * fmaf(t * t, 0.0356774081f, 0.7978845608f);
                        const float e = __builtin_amdgcn_exp2f(u * -2.88539008178f);
                        t = t * __builtin_amdgcn_rcpf(1.0f + e) * LOG2E;
                    }
                    SMEM[row * 136 + col] = (half_t)t;
                }
            }
        }
        __syncthreads();
        const int cc = tid & 15;
        const int rr = tid >> 4;
        #pragma unroll
        for (int p = 0; p < 4; ++p) {
            const int row = p * 32 + rr;
            const h8 v = *(const h8*)&SMEM[row * 136 + cc * 8];
            *(h8*)(outp + (size_t)(m0 + row) * D_ + n0 + cc * 8) = v;
        }
    }
}

// ---------------------------------------------------------------------------
// Kernel 2: flash attention — exact r7 winner (58.0 µs): 128 q-rows per
// block, 8 waves (16 q-rows/wave), alias-free static double-buffer,
// x2-unrolled loop, one barrier per tile, T13 defer-max, setprio,
// XCD-bijective swizzle.  (r8's dual-q 4-wave variant reverted: occupancy
// 19% -> latency-bound, 75.5 µs.  Session law: waves/SIMD first.)
// ---------------------------------------------------------------------------
#define DEFER_THR 10.0f
#define ATTN_TILE(KS, VS)                                                     \
    do {                                                                      \
        f32x4 sa[4];                                                          \
        __builtin_amdgcn_s_setprio(1);                                        \
        _Pragma("unroll")                                                     \
        for (int j = 0; j < 4; ++j) {                                         \
            const int rK = j * 16 + ln;                                       \
            const h8 ka0 = *(const h8*)&KS[rK * 64 + ((quad)     ^ (rK & 7)) * 8]; \
            const h8 ka1 = *(const h8*)&KS[rK * 64 + ((quad + 4) ^ (rK & 7)) * 8]; \
            f32x4 t = (f32x4){0.f, 0.f, 0.f, 0.f};                            \
            t = __builtin_amdgcn_mfma_f32_16x16x32_f16(ka0, qa0, t, 0, 0, 0); \
            t = __builtin_amdgcn_mfma_f32_16x16x32_f16(ka1, qa1, t, 0, 0, 0); \
            sa[j] = t;                                                        \
        }                                                                     \
        __builtin_amdgcn_s_setprio(0);                                        \
        float mxa = sa[0][0];                                                 \
        _Pragma("unroll")                                                     \
        for (int j = 0; j < 4; ++j)                                           \
            _Pragma("unroll")                                                 \
            for (int r = 0; r < 4; ++r) mxa = fmaxf(mxa, sa[j][r]);           \
        mxa = fmaxf(mxa, __shfl_xor(mxa, 16, 64));                            \
        mxa = fmaxf(mxa, __shfl_xor(mxa, 32, 64));                            \
        if (__ballot(mxa > m_a + DEFER_THR)) {                                \
            const float mna = fmaxf(m_a, mxa);                                \
            const float ala = __builtin_amdgcn_exp2f(m_a - mna);              \
            m_a = mna;                                                        \
            float ra[4];                                                      \
            _Pragma("unroll")                                                 \
            for (int r = 0; r < 4; ++r) ra[r] = __shfl(ala, quad * 4 + r, 64);\
            _Pragma("unroll")                                                 \
            for (int r = 0; r < 4; ++r) {                                     \
                la[r] *= ra[r];                                               \
                _Pragma("unroll")                                             \
                for (int j = 0; j < 4; ++j) Oa[j][r] *= ra[r];                \
            }                                                                 \
        }                                                                     \
        _Pragma("unroll")                                                     \
        for (int j = 0; j < 4; ++j) {                                         \
            h4 pva;                                                           \
            _Pragma("unroll")                                                 \
            for (int r = 0; r < 4; ++r)                                       \
                pva[r] = (half_t)__builtin_amdgcn_exp2f(sa[j][r] - m_a);      \
            *(h4*)&QPs[wave * 16 + ln][j * 16 + quad * 4] = pva;              \
        }                                                                     \
        const h8 pa0 = *(const h8*)&QPs[wave * 16 + ln][quad * 8];            \
        const h8 pa1 = *(const h8*)&QPs[wave * 16 + ln][32 + quad * 8];       \
        __builtin_amdgcn_s_setprio(1);                                        \
        _Pragma("unroll")                                                     \
        for (int j = 0; j < 4; ++j) {                                         \
            const int rV = j * 16 + ln;                                       \
            const h8 vb0 = *(const h8*)&VS[rV * 64 + ((quad)     ^ (rV & 7)) * 8]; \
            const h8 vb1 = *(const h8*)&VS[rV * 64 + ((quad + 4) ^ (rV & 7)) * 8]; \
            Oa[j] = __builtin_amdgcn_mfma_f32_16x16x32_f16(pa0, vb0, Oa[j], 0, 0, 0); \
            Oa[j] = __builtin_amdgcn_mfma_f32_16x16x32_f16(pa1, vb1, Oa[j], 0, 0, 0); \
        }                                                                     \
        la = __builtin_amdgcn_mfma_f32_16x16x32_f16(pa0, ones8, la, 0, 0, 0); \
        la = __builtin_amdgcn_mfma_f32_16x16x32_f16(pa1, ones8, la, 0, 0, 0); \
        __builtin_amdgcn_s_setprio(0);                                        \
    } while (0)

__global__ __launch_bounds__(512) void attn_f16(
    const half_t* __restrict__ Q, const half_t* __restrict__ K,
    const half_t* __restrict__ Vt, float* __restrict__ out)
{
    const int tid  = threadIdx.x;
    const int lane = tid & 63;
    const int wave = tid >> 6;           // 0..7
    const int ln   = lane & 15;
    const int quad = lane >> 4;

    // XCD-bijective swizzle: 512 blocks = 8 x 64
    const int lin = blockIdx.y * 16 + blockIdx.x;        // 0..511
    const int swz = (lin & 7) * 64 + (lin >> 3);
    const int bh  = swz >> 4;            // 0..31
    const int b   = bh >> 4;
    const int h   = bh & 15;
    const int q0  = (swz & 15) * 128;

    const half_t* __restrict__ Qb  = Q  + (size_t)b * S_ * D_ + h * DH_;
    const half_t* __restrict__ Kb  = K  + (size_t)b * S_ * D_ + h * DH_;
    const half_t* __restrict__ Vtb = Vt + (size_t)bh * DH_ * S_;

    // four DISTINCT static buffers -> alias-free prefetch (r3)
    __shared__ __align__(16) half_t Ks0[64 * 64];
    __shared__ __align__(16) half_t Vs0[64 * 64];
    __shared__ __align__(16) half_t Ks1[64 * 64];
    __shared__ __align__(16) half_t Vs1[64 * 64];
    __shared__ __align__(16) half_t QPs[128][72];   // Q tile, then P bands

    // per-thread staging addresses (advance by fixed stride per staged tile)
    const int sr  = tid >> 3, sc0 = tid & 7;
    const int scs = sc0 ^ (sr & 7);
    const half_t* kS = Kb  + (size_t)sr * D_ + scs * 8;   // += 64*D_ per tile
    const half_t* vS = Vtb + (size_t)sr * S_ + scs * 8;   // += 64   per tile
    half_t* const kD0 = &Ks0[tid * 8];
    half_t* const vD0 = &Vs0[tid * 8];
    half_t* const kD1 = &Ks1[tid * 8];
    half_t* const vD1 = &Vs1[tid * 8];

    // ---- prologue: stage tile 0 into buffer 0 (overlaps the Q load) ----
    gll16(kS, kD0); gll16(vS, vD0);
    kS += 64 * D_; vS += 64;

    // ---- load Q tile (128x64), hoist the wave's Q fragment pair ----
    #pragma unroll
    for (int l = 0; l < 2; ++l) {
        const int c = tid + l * 512;                 // 0..1023
        const int r = c >> 3, k8 = c & 7;
        *(h8*)&QPs[r][k8 * 8] = *(const h8*)(Qb + (size_t)(q0 + r) * D_ + k8 * 8);
    }
    __syncthreads();    // implicit vmcnt(0)+lgkmcnt(0): Q AND tile-0 ready
    const h8 qa0 = *(const h8*)&QPs[wave * 16 + ln][quad * 8];
    const h8 qa1 = *(const h8*)&QPs[wave * 16 + ln][32 + quad * 8];

    h8 ones8;
    #pragma unroll
    for (int t = 0; t < 8; ++t) ones8[t] = (half_t)1.0f;

    f32x4 Oa[4];
    #pragma unroll
    for (int j = 0; j < 4; ++j) Oa[j] = (f32x4){0.f, 0.f, 0.f, 0.f};
    f32x4 la = (f32x4){0.f, 0.f, 0.f, 0.f};
    float m_a = -INFINITY;               // q-row = wave*16 + ln

    // 32 k-tiles, unrolled x2: buffer identity is compile-time constant.
    for (int it = 0; it < 16; ++it) {
        // phase A: prefetch tile (2it+1) into buf1, compute buf0 (tile 2it)
        gll16(kS, kD1); gll16(vS, vD1);
        kS += 64 * D_; vS += 64;
        ATTN_TILE(Ks0, Vs0);
        __syncthreads();          // drains buf1 DMA; all done reading buf0

        // phase B: prefetch tile (2it+2) into buf0, compute buf1 (tile 2it+1)
        if (it < 15) {
            gll16(kS, kD0); gll16(vS, vD0);
            kS += 64 * D_; vS += 64;
        }
        ATTN_TILE(Ks1, Vs1);
        __syncthreads();          // drains buf0 DMA; all done reading buf1
    }

    // ---- epilogue: normalize, store fp32 ----
    #pragma unroll
    for (int r = 0; r < 4; ++r) {
        const float iva = 1.0f / la[r];
        const int rowa = q0 + wave * 16 + quad * 4 + r;
        #pragma unroll
        for (int j = 0; j < 4; ++j)
            out[((size_t)b * S_ + rowa) * D_ + h * DH_ + j * 16 + ln] = Oa[j][r] * iva;
    }
}

// ---------------------------------------------------------------------------
extern "C" void kernel_launch(void* const* d_in, const int* in_sizes, int n_in,
                              void* d_out, int out_size, void* d_ws, size_t ws_size,
                              hipStream_t stream) {
    const float* x  = (const float*)d_in[0];
    const float* Wq = (const float*)d_in[1];
    const float* bq = (const float*)d_in[2];
    const float* Wk = (const float*)d_in[3];
    const float* bk = (const float*)d_in[4];
    const float* Wv = (const float*)d_in[5];
    const float* bv = (const float*)d_in[6];
    float* out = (float*)d_out;

    const size_t nmd = (size_t)M_ * D_;   // 4M
    const size_t ndd = (size_t)D_ * D_;   // 1M
    half_t* xh  = (half_t*)d_ws;          // 4M halves
    half_t* Wt  = xh + nmd;               // 3M
    half_t* Qh  = Wt + 3 * ndd;           // 4M
    half_t* Kh  = Qh + nmd;               // 4M
    half_t* Vtw = Kh + nmd;               // 4M  (38 MB total)

    prep_k<<<2048 + 1536, 256, 0, stream>>>(x, xh, Wq, Wk, Wv, Wt);
    qkv_gemm_f16<<<dim3(3 * D_ / 128, M_ / 128), 512, 0, stream>>>(
        xh, Wt, bq, bk, bv, Qh, Kh, Vtw);
    attn_f16<<<dim3(S_ / 128, B_ * H_), 512, 0, stream>>>(Qh, Kh, Vtw, out);
}